// Round 1
// baseline (2549.367 us; speedup 1.0000x reference)
//
#include <hip/hip_runtime.h>
#include <hip/hip_bf16.h>

typedef unsigned short ushort;
typedef __attribute__((ext_vector_type(8))) short short8;   // 8 bf16 (4 VGPRs) MFMA operand
typedef __attribute__((ext_vector_type(4))) float floatx4;  // MFMA accumulator

#define TB   1024   // T
#define BB   4      // B
#define HH   1024   // H
#define KK   512    // K (gate dim)
#define VD   1024   // Vd
#define OO   1024   // O
#define NVOC 32000
#define NL   2
#define NTOK (BB*TB)
#define NHALF 16000  // W_head transposed+GEMMed in two column chunks (ws budget)

__device__ __forceinline__ float bf2f(ushort u) { return __uint_as_float(((unsigned)u) << 16); }
__device__ __forceinline__ ushort f2bf(float f) {
    unsigned x = __float_as_uint(f);
    return (ushort)((x + 0x7fffu + ((x >> 16) & 1u)) >> 16);   // RNE
}

// async global->LDS 16B: LDS dest = wave-uniform base + lane*16 (m97 pattern)
__device__ __forceinline__ void gld16(void* dst, const void* src) {
    __builtin_amdgcn_global_load_lds(
        (__attribute__((address_space(1))) void*)(void*)src,
        (__attribute__((address_space(3))) void*)dst, 16, 0, 0);
}

// ---------------- dtype probe: fp32 data read as bf16 contains huge values ----------------
__global__ void probe_k(const ushort* __restrict__ emb, int* __restrict__ flag) {
    __shared__ int any;
    if (threadIdx.x == 0) any = 0;
    __syncthreads();
    int bad = 0;
    for (int i = threadIdx.x; i < 32768; i += 256) {
        float a = fabsf(bf2f(emb[i]));
        if (a > 1e6f) bad = 1;
    }
    if (bad) any = 1;
    __syncthreads();
    if (threadIdx.x == 0) *flag = any;
}

// ---------------- bias normalize to bf16 ----------------
__global__ void cvt_bias_k(const void* __restrict__ src, ushort* __restrict__ dst, int n,
                           const int* __restrict__ flagp) {
    int i = blockIdx.x * 256 + threadIdx.x;
    if (i >= n) return;
    if (*flagp) dst[i] = f2bf(((const float*)src)[i]);
    else        dst[i] = ((const ushort*)src)[i];
}

// ---------------- transpose: in (R,C) row-major (+element offset) -> out (C,R) bf16 ----------------
__global__ __launch_bounds__(256) void transpose_k(const void* __restrict__ in_, size_t eoff,
                                                   ushort* __restrict__ out, int R, int C,
                                                   const int* __restrict__ flagp) {
    __shared__ ushort tile[32][33];
    const int bx = blockIdx.x * 32;
    const int by = blockIdx.y * 32;
    const int tx = threadIdx.x & 31;
    const int ty = threadIdx.x >> 5;
    if (*flagp) {
        const float* in = (const float*)in_ + eoff;
#pragma unroll
        for (int i = 0; i < 32; i += 8)
            tile[ty + i][tx] = f2bf(in[(size_t)(by + ty + i) * C + bx + tx]);
    } else {
        const ushort* in = (const ushort*)in_ + eoff;
#pragma unroll
        for (int i = 0; i < 32; i += 8)
            tile[ty + i][tx] = in[(size_t)(by + ty + i) * C + bx + tx];
    }
    __syncthreads();
#pragma unroll
    for (int i = 0; i < 32; i += 8)
        out[(size_t)(bx + ty + i) * R + by + tx] = tile[tx][ty + i];
}

// ---------------- embedding gather ----------------
__global__ __launch_bounds__(256) void gather_k(const int* __restrict__ ids,
                                                const void* __restrict__ emb_,
                                                ushort* __restrict__ h,
                                                const int* __restrict__ flagp) {
    int t = blockIdx.x;
    int id = ids[t];
    int c = threadIdx.x * 4;
    if (*flagp) {
        const float* emb = (const float*)emb_;
        float4 v = *(const float4*)&emb[(size_t)id * HH + c];
        ushort4 o; o.x = f2bf(v.x); o.y = f2bf(v.y); o.z = f2bf(v.z); o.w = f2bf(v.w);
        *(ushort4*)&h[(size_t)t * HH + c] = o;
    } else {
        const ushort* emb = (const ushort*)emb_;
        *(uint2*)&h[(size_t)t * HH + c] = *(const uint2*)&emb[(size_t)id * HH + c];
    }
}

// ---------------- bf16 GEMM, B pre-transposed (m97 structure: global_load_lds staging) ----------------
// MODE 0: bf16 out, single bias. MODE 1: fp32 out, fused qkgv epilogue (q | sig(k) | sig(g) | v).
// MODE 2: head — out dtype switched on *flagp.
// Tile 128x128x32, 256 threads = 4 waves (2x2 of 64x64), v_mfma_f32_16x16x32_bf16.
template<int MODE>
__global__ __launch_bounds__(256) void gemm_bt(
    const ushort* __restrict__ A, const ushort* __restrict__ Bt, void* __restrict__ Cv,
    const ushort* __restrict__ b0, const ushort* __restrict__ b1,
    const ushort* __restrict__ b2, const ushort* __restrict__ b3,
    int K, int ldc, int coloff, const int* __restrict__ flagp)
{
    // linear (unpadded) tiles: global_load_lds writes base + lane*16, so layout must be lane-linear
    __shared__ ushort As[128][32];
    __shared__ ushort Bs[128][32];

    const int tid  = threadIdx.x;
    const int bm   = blockIdx.y * 128;
    const int bn   = blockIdx.x * 128;
    const int wave = tid >> 6, lane = tid & 63;
    const int wm   = (wave >> 1) * 64, wn = (wave & 1) * 64;
    const int l15  = lane & 15, quad = lane >> 4;

    floatx4 acc[4][4];
#pragma unroll
    for (int i = 0; i < 4; i++)
#pragma unroll
        for (int j = 0; j < 4; j++) acc[i][j] = (floatx4){0.f, 0.f, 0.f, 0.f};

    // staging: wave w async-copies rows [w*16, w*16+16) and [64+w*16, 64+w*16+16) of A and B.
    // lane l -> row w*16 + l/4, col (l%4)*8 (16B), matching LDS linear order exactly.
    const int srow = wave * 16 + (lane >> 2);
    const int scol = (lane & 3) * 8;
    const ushort* aS0 = A  + (size_t)(bm + srow) * K + scol;
    const ushort* aS1 = aS0 + (size_t)64 * K;
    const ushort* bS0 = Bt + (size_t)(bn + srow) * K + scol;
    const ushort* bS1 = bS0 + (size_t)64 * K;
    ushort* aD0 = &As[wave * 16][0];
    ushort* aD1 = &As[64 + wave * 16][0];
    ushort* bD0 = &Bs[wave * 16][0];
    ushort* bD1 = &Bs[64 + wave * 16][0];

    for (int kt = 0; kt < K; kt += 32) {
        gld16(aD0, aS0 + kt);
        gld16(aD1, aS1 + kt);
        gld16(bD0, bS0 + kt);
        gld16(bD1, bS1 + kt);
        __syncthreads();   // compiler drains vmcnt before s_barrier (m97)

        short8 af[4], bfr[4];
#pragma unroll
        for (int i = 0; i < 4; i++) af[i]  = *(const short8*)&As[wm + i * 16 + l15][quad * 8];
#pragma unroll
        for (int i = 0; i < 4; i++) bfr[i] = *(const short8*)&Bs[wn + i * 16 + l15][quad * 8];
#pragma unroll
        for (int i = 0; i < 4; i++)
#pragma unroll
            for (int j = 0; j < 4; j++)
                acc[i][j] = __builtin_amdgcn_mfma_f32_16x16x32_bf16(af[i], bfr[j], acc[i][j], 0, 0, 0);
        __syncthreads();
    }

    const int f = (MODE == 2) ? *flagp : 0;

    // epilogue: D lane map col=lane&15, row=quad*4+r (verified m89/m91)
#pragma unroll
    for (int i = 0; i < 4; i++) {
#pragma unroll
        for (int j = 0; j < 4; j++) {
            const int col = bn + wn + j * 16 + l15;
            float bias; bool sig = false;
            if (MODE == 1) {
                if      (col < KK)     { bias = bf2f(b0[col]); }
                else if (col < 2 * KK) { bias = bf2f(b1[col - KK]);     sig = true; }
                else if (col < 3 * KK) { bias = bf2f(b2[col - 2 * KK]); sig = true; }
                else                   { bias = bf2f(b3[col - 3 * KK]); }
            } else {
                bias = bf2f(b0[col]);
            }
#pragma unroll
            for (int r = 0; r < 4; r++) {
                const int row = bm + wm + i * 16 + quad * 4 + r;
                float v = acc[i][j][r] + bias;
                if (sig) v = 1.f / (1.f + __expf(-v));
                const size_t idx = (size_t)row * ldc + coloff + col;
                if (MODE == 1)      ((float*)Cv)[idx]  = v;
                else if (MODE == 0) ((ushort*)Cv)[idx] = f2bf(v);
                else { if (f) ((float*)Cv)[idx] = v; else ((ushort*)Cv)[idx] = f2bf(v); }
            }
        }
    }
}

// ---------------- sequential gated scan (restructured) ----------------
// qkgv: (B*T, 2560) fp32 rows = [q(512) | k(512) | g(512) | v(1024)]
// out:  (B*T, 1024) bf16.
// grid (VD/16, B), 256 thr. NEW thread map: all 16 k-groups of one v live in ONE wave:
//   kg = lane>>2 (32 k each), vl = lane&3, v = v0 + wave*4 + vl  -> reduce = 4 shfl_xor, no LDS.
// Triple-buffered LDS, ONE barrier/step. Distance-3 register pipeline (T14): iter t
//   ds-writes row t+1 (loaded at t-2, latency long gone), issues float4 loads for row t+3.
// LDS slots bank-rotated: float4 #i4 of each 512-array at slot hi*32 + (4*(lo+hi) & 31),
//   hi=i4>>3, lo=i4&7 -> per-wave reads hit all 8 16B bank-groups 2x (free, m136).
__device__ __forceinline__ int qslot(int i4) {   // i4 = float4 index 0..127
    const int hi = i4 >> 3, lo = i4 & 7;
    return hi * 32 + ((4 * (lo + hi)) & 31);
}

__global__ __launch_bounds__(256) void scan_k(const float* __restrict__ qkgv,
                                              ushort* __restrict__ outp)
{
    const int b   = blockIdx.y;
    const int v0  = blockIdx.x * 16;
    const int tid = threadIdx.x;
    const int lane = tid & 63;
    const int wave = tid >> 6;
    const int kg   = lane >> 2;          // 0..15: k-group of 32
    const int vl   = lane & 3;
    const int kb   = kg * 32;
    const int vloc = wave * 4 + vl;      // 0..15 local v
    const int myv  = v0 + vloc;

    __shared__ float sq[3][512], sk[3][512], sg[3][512];
    __shared__ float sv[3][16];

    float s[32];
#pragma unroll
    for (int j = 0; j < 32; j++) s[j] = 0.f;

    const size_t rowbase = (size_t)b * TB * 2560;

    // staging map: thread stages float4 #tid (q for tid<128, k for tid>=128) and,
    // for tid<132, float4 #(tid+256) (g for tid<128, v chunk for tid 128..131).
    const int slot0 = qslot(tid & 127);
    const int off0  = (tid < 128) ? tid * 4 : 512 + (tid - 128) * 4;
    const int off1  = (tid < 128) ? 1024 + tid * 4 : 1536 + v0 + (tid - 128) * 4;

    float4 A0 = {0,0,0,0}, A1 = {0,0,0,0}, A2 = {0,0,0,0};
    float4 B0 = {0,0,0,0}, B1 = {0,0,0,0}, B2 = {0,0,0,0};

    { // prologue: load rows 0,1,2 into reg sets 0,1,2; stage row 0 -> buf 0
        const float* r0 = qkgv + rowbase;
        A0 = *(const float4*)&r0[off0];
        A1 = *(const float4*)&r0[2560 + off0];
        A2 = *(const float4*)&r0[5120 + off0];
        if (tid < 132) {
            B0 = *(const float4*)&r0[off1];
            B1 = *(const float4*)&r0[2560 + off1];
            B2 = *(const float4*)&r0[5120 + off1];
        }
        float* dqk = (tid < 128) ? &sq[0][0] : &sk[0][0];
        *(float4*)&dqk[slot0] = A0;
        if (tid < 132) {
            if (tid < 128) *(float4*)&sg[0][slot0] = B0;
            else           *(float4*)&sv[0][(tid - 128) * 4] = B0;
        }
        __syncthreads();
    }

    // iter T: ds_write reg set (T+1)%3 (row T+1) -> buf (T+1)%3; load row T+3 -> set T%3;
    //         compute row T from buf T%3; reduce in-wave; one barrier.
#define SCAN_STEP(T, RW_A, RW_B, RL_A, RL_B, BW_, BC_)                              \
    {                                                                               \
        const int t_ = (T);                                                         \
        if (t_ + 1 < TB) {                                                          \
            float* dqk_ = (tid < 128) ? &sq[BW_][0] : &sk[BW_][0];                  \
            *(float4*)&dqk_[slot0] = RW_A;                                          \
            if (tid < 132) {                                                        \
                if (tid < 128) *(float4*)&sg[BW_][slot0] = RW_B;                    \
                else           *(float4*)&sv[BW_][(tid - 128) * 4] = RW_B;          \
            }                                                                       \
        }                                                                           \
        if (t_ + 3 < TB) {                                                          \
            const float* row_ = qkgv + rowbase + (size_t)(t_ + 3) * 2560;           \
            RL_A = *(const float4*)&row_[off0];                                     \
            if (tid < 132) RL_B = *(const float4*)&row_[off1];                      \
        }                                                                           \
        if (t_ < TB) {                                                              \
            const float vv = sv[BC_][vloc];                                         \
            float po = 0.f;                                                         \
            _Pragma("unroll")                                                       \
            for (int m = 0; m < 8; m++) {                                           \
                const int off = ((m + kg) * 4) & 31;                                \
                float4 g4 = *(const float4*)&sg[BC_][kb + off];                     \
                float4 k4 = *(const float4*)&sk[BC_][kb + off];                     \
                float4 q4 = *(const float4*)&sq[BC_][kb + off];                     \
                s[m*4+0] = fmaf(s[m*4+0], g4.x, k4.x * vv); po = fmaf(q4.x, s[m*4+0], po); \
                s[m*4+1] = fmaf(s[m*4+1], g4.y, k4.y * vv); po = fmaf(q4.y, s[m*4+1], po); \
                s[m*4+2] = fmaf(s[m*4+2], g4.z, k4.z * vv); po = fmaf(q4.z, s[m*4+2], po); \
                s[m*4+3] = fmaf(s[m*4+3], g4.w, k4.w * vv); po = fmaf(q4.w, s[m*4+3], po); \
            }                                                                       \
            po += __shfl_xor(po, 4, 64);                                            \
            po += __shfl_xor(po, 8, 64);                                            \
            po += __shfl_xor(po, 16, 64);                                           \
            po += __shfl_xor(po, 32, 64);                                           \
            if (kg == 0) outp[((size_t)b * TB + t_) * VD + myv] = f2bf(po);         \
        }                                                                           \
        __syncthreads();                                                            \
    }

    for (int t = 0; t < TB; t += 3) {
        SCAN_STEP(t,     A1, B1, A0, B0, 1, 0);
        SCAN_STEP(t + 1, A2, B2, A1, B1, 2, 1);
        SCAN_STEP(t + 2, A0, B0, A2, B2, 0, 2);
    }
#undef SCAN_STEP
}

extern "C" void kernel_launch(void* const* d_in, const int* in_sizes, int n_in,
                              void* d_out, int out_size, void* d_ws, size_t ws_size,
                              hipStream_t stream) {
    const int*  ids = (const int*)d_in[0];
    const void* emb = d_in[1];
    const void* Wq  = d_in[2];
    const void* bq  = d_in[3];
    const void* Wk  = d_in[4];
    const void* bk  = d_in[5];
    const void* Wg  = d_in[6];
    const void* bg  = d_in[7];
    const void* Wv  = d_in[8];
    const void* bv  = d_in[9];
    const void* Wo  = d_in[10];
    const void* bo  = d_in[11];
    const void* Wh  = d_in[12];
    const void* bh  = d_in[13];
    (void)in_sizes; (void)n_in; (void)out_size; (void)ws_size;

    // ---- ws layout (~56 MB total) ----
    char* p = (char*)d_ws;
    auto alloc = [&](size_t bytes) { char* r = p; p += (bytes + 255) & ~(size_t)255; return (void*)r; };
    int*    flagp = (int*)alloc(4);
    ushort* biasc = (ushort*)alloc((size_t)39168 * 2);
    ushort* bqc = biasc, *bkc = biasc + 1024, *bgc = biasc + 2048;
    ushort* bvc = biasc + 3072, *boc = biasc + 5120, *bhc = biasc + 7168;
    ushort* Wcat  = (ushort*)alloc((size_t)NL * 2560 * HH * 2);
    ushort* Wot   = (ushort*)alloc((size_t)NL * OO * VD * 2);
    ushort* h     = (ushort*)alloc((size_t)NTOK * HH * 2);
    ushort* Whalf = (ushort*)alloc((size_t)NHALF * OO * 2);

    // ---- transient buffers live inside d_out (dead before head GEMM writes it) ----
    float*  qkgv  = (float*)d_out;
    ushort* scano = (ushort*)((char*)d_out + (size_t)NTOK * 2560 * 4);

    // ---- dtype probe + bias normalize ----
    probe_k<<<1, 256, 0, stream>>>((const ushort*)emb, flagp);
    cvt_bias_k<<<(NL*KK + 255) / 256, 256, 0, stream>>>(bq, bqc, NL*KK, flagp);
    cvt_bias_k<<<(NL*KK + 255) / 256, 256, 0, stream>>>(bk, bkc, NL*KK, flagp);
    cvt_bias_k<<<(NL*KK + 255) / 256, 256, 0, stream>>>(bg, bgc, NL*KK, flagp);
    cvt_bias_k<<<(NL*VD + 255) / 256, 256, 0, stream>>>(bv, bvc, NL*VD, flagp);
    cvt_bias_k<<<(NL*OO + 255) / 256, 256, 0, stream>>>(bo, boc, NL*OO, flagp);
    cvt_bias_k<<<(NVOC  + 255) / 256, 256, 0, stream>>>(bh, bhc, NVOC,  flagp);

    // ---- weight transposes (normalize to bf16) ----
    for (int l = 0; l < NL; l++) {
        ushort* Wc = Wcat + (size_t)l * 2560 * HH;
        transpose_k<<<dim3(KK/32, HH/32), 256, 0, stream>>>(Wq, (size_t)l*HH*KK, Wc,                   HH, KK, flagp);
        transpose_k<<<dim3(KK/32, HH/32), 256, 0, stream>>>(Wk, (size_t)l*HH*KK, Wc + (size_t)KK*HH,   HH, KK, flagp);
        transpose_k<<<dim3(KK/32, HH/32), 256, 0, stream>>>(Wg, (size_t)l*HH*KK, Wc + (size_t)2*KK*HH, HH, KK, flagp);
        transpose_k<<<dim3(VD/32, HH/32), 256, 0, stream>>>(Wv, (size_t)l*HH*VD, Wc + (size_t)3*KK*HH, HH, VD, flagp);
        transpose_k<<<dim3(OO/32, VD/32), 256, 0, stream>>>(Wo, (size_t)l*VD*OO, Wot + (size_t)l*OO*VD, VD, OO, flagp);
    }

    // ---- embedding ----
    gather_k<<<NTOK, 256, 0, stream>>>(ids, emb, h, flagp);

    // ---- layers ----
    for (int l = 0; l < NL; l++) {
        const ushort* Wc = Wcat + (size_t)l * 2560 * HH;
        gemm_bt<1><<<dim3(2560/128, NTOK/128), 256, 0, stream>>>(
            h, Wc, qkgv, bqc + l*KK, bkc + l*KK, bgc + l*KK, bvc + l*VD,
            HH, 2560, 0, flagp);
        scan_k<<<dim3(VD/16, BB), 256, 0, stream>>>(qkgv, scano);
        gemm_bt<0><<<dim3(OO/128, NTOK/128), 256, 0, stream>>>(
            scano, Wot + (size_t)l*OO*VD, h, boc + l*OO, nullptr, nullptr, nullptr,
            VD, OO, 0, flagp);
    }

    // ---- LM head: transpose W_head chunk -> GEMM, twice (ws budget) ----
    for (int c0 = 0; c0 < NVOC; c0 += NHALF) {
        transpose_k<<<dim3(NHALF/32, OO/32), 256, 0, stream>>>(Wh, (size_t)c0, Whalf, OO, NVOC, flagp);
        gemm_bt<2><<<dim3(NHALF/128, NTOK/128), 256, 0, stream>>>(
            h, Whalf, d_out, bhc + c0, nullptr, nullptr, nullptr,
            OO, NVOC, c0, flagp);
    }
}

// Round 2
// 2450.449 us; speedup vs baseline: 1.0404x; 1.0404x over previous
//
#include <hip/hip_runtime.h>
#include <hip/hip_bf16.h>

typedef unsigned short ushort;
typedef __attribute__((ext_vector_type(8))) short short8;   // 8 bf16 (4 VGPRs) MFMA operand
typedef __attribute__((ext_vector_type(4))) float floatx4;  // MFMA accumulator

#define TB   1024   // T
#define BB   4      // B
#define HH   1024   // H
#define KK   512    // K (gate dim)
#define VD   1024   // Vd
#define OO   1024   // O
#define NVOC 32000
#define NL   2
#define NTOK (BB*TB)
#define NHALF 16000  // W_head transposed+GEMMed in two column chunks (ws budget)

__device__ __forceinline__ float bf2f(ushort u) { return __uint_as_float(((unsigned)u) << 16); }
__device__ __forceinline__ ushort f2bf(float f) {
    unsigned x = __float_as_uint(f);
    return (ushort)((x + 0x7fffu + ((x >> 16) & 1u)) >> 16);   // RNE
}

// async global->LDS 16B: LDS dest = wave-uniform base + lane*16 (m97 pattern)
__device__ __forceinline__ void gld16(void* dst, const void* src) {
    __builtin_amdgcn_global_load_lds(
        (__attribute__((address_space(1))) void*)(void*)src,
        (__attribute__((address_space(3))) void*)dst, 16, 0, 0);
}

// ---------------- dtype probe: fp32 data read as bf16 contains huge values ----------------
__global__ void probe_k(const ushort* __restrict__ emb, int* __restrict__ flag) {
    __shared__ int any;
    if (threadIdx.x == 0) any = 0;
    __syncthreads();
    int bad = 0;
    for (int i = threadIdx.x; i < 32768; i += 256) {
        float a = fabsf(bf2f(emb[i]));
        if (a > 1e6f) bad = 1;
    }
    if (bad) any = 1;
    __syncthreads();
    if (threadIdx.x == 0) *flag = any;
}

// ---------------- bias normalize to bf16 ----------------
__global__ void cvt_bias_k(const void* __restrict__ src, ushort* __restrict__ dst, int n,
                           const int* __restrict__ flagp) {
    int i = blockIdx.x * 256 + threadIdx.x;
    if (i >= n) return;
    if (*flagp) dst[i] = f2bf(((const float*)src)[i]);
    else        dst[i] = ((const ushort*)src)[i];
}

// ---------------- transpose: in (R,C) row-major (+element offset) -> out (C,R) bf16 ----------------
__global__ __launch_bounds__(256) void transpose_k(const void* __restrict__ in_, size_t eoff,
                                                   ushort* __restrict__ out, int R, int C,
                                                   const int* __restrict__ flagp) {
    __shared__ ushort tile[32][33];
    const int bx = blockIdx.x * 32;
    const int by = blockIdx.y * 32;
    const int tx = threadIdx.x & 31;
    const int ty = threadIdx.x >> 5;
    if (*flagp) {
        const float* in = (const float*)in_ + eoff;
#pragma unroll
        for (int i = 0; i < 32; i += 8)
            tile[ty + i][tx] = f2bf(in[(size_t)(by + ty + i) * C + bx + tx]);
    } else {
        const ushort* in = (const ushort*)in_ + eoff;
#pragma unroll
        for (int i = 0; i < 32; i += 8)
            tile[ty + i][tx] = in[(size_t)(by + ty + i) * C + bx + tx];
    }
    __syncthreads();
#pragma unroll
    for (int i = 0; i < 32; i += 8)
        out[(size_t)(bx + ty + i) * R + by + tx] = tile[tx][ty + i];
}

// ---------------- embedding gather ----------------
__global__ __launch_bounds__(256) void gather_k(const int* __restrict__ ids,
                                                const void* __restrict__ emb_,
                                                ushort* __restrict__ h,
                                                const int* __restrict__ flagp) {
    int t = blockIdx.x;
    int id = ids[t];
    int c = threadIdx.x * 4;
    if (*flagp) {
        const float* emb = (const float*)emb_;
        float4 v = *(const float4*)&emb[(size_t)id * HH + c];
        ushort4 o; o.x = f2bf(v.x); o.y = f2bf(v.y); o.z = f2bf(v.z); o.w = f2bf(v.w);
        *(ushort4*)&h[(size_t)t * HH + c] = o;
    } else {
        const ushort* emb = (const ushort*)emb_;
        *(uint2*)&h[(size_t)t * HH + c] = *(const uint2*)&emb[(size_t)id * HH + c];
    }
}

// ---------------- bf16 GEMM, B pre-transposed (m97 structure: global_load_lds staging) ----------------
// MODE 0: bf16 out, single bias. MODE 1: fp32 out, fused qkgv epilogue (q | sig(k) | sig(g) | v).
// MODE 2: head — out dtype switched on *flagp.
// Tile 128x128x32, 256 threads = 4 waves (2x2 of 64x64), v_mfma_f32_16x16x32_bf16.
template<int MODE>
__global__ __launch_bounds__(256) void gemm_bt(
    const ushort* __restrict__ A, const ushort* __restrict__ Bt, void* __restrict__ Cv,
    const ushort* __restrict__ b0, const ushort* __restrict__ b1,
    const ushort* __restrict__ b2, const ushort* __restrict__ b3,
    int K, int ldc, int coloff, const int* __restrict__ flagp)
{
    // linear (unpadded) tiles: global_load_lds writes base + lane*16, so layout must be lane-linear
    __shared__ ushort As[128][32];
    __shared__ ushort Bs[128][32];

    const int tid  = threadIdx.x;
    const int bm   = blockIdx.y * 128;
    const int bn   = blockIdx.x * 128;
    const int wave = tid >> 6, lane = tid & 63;
    const int wm   = (wave >> 1) * 64, wn = (wave & 1) * 64;
    const int l15  = lane & 15, quad = lane >> 4;

    floatx4 acc[4][4];
#pragma unroll
    for (int i = 0; i < 4; i++)
#pragma unroll
        for (int j = 0; j < 4; j++) acc[i][j] = (floatx4){0.f, 0.f, 0.f, 0.f};

    // staging: wave w async-copies rows [w*16, w*16+16) and [64+w*16, 64+w*16+16) of A and B.
    // lane l -> row w*16 + l/4, col (l%4)*8 (16B), matching LDS linear order exactly.
    const int srow = wave * 16 + (lane >> 2);
    const int scol = (lane & 3) * 8;
    const ushort* aS0 = A  + (size_t)(bm + srow) * K + scol;
    const ushort* aS1 = aS0 + (size_t)64 * K;
    const ushort* bS0 = Bt + (size_t)(bn + srow) * K + scol;
    const ushort* bS1 = bS0 + (size_t)64 * K;
    ushort* aD0 = &As[wave * 16][0];
    ushort* aD1 = &As[64 + wave * 16][0];
    ushort* bD0 = &Bs[wave * 16][0];
    ushort* bD1 = &Bs[64 + wave * 16][0];

    for (int kt = 0; kt < K; kt += 32) {
        gld16(aD0, aS0 + kt);
        gld16(aD1, aS1 + kt);
        gld16(bD0, bS0 + kt);
        gld16(bD1, bS1 + kt);
        __syncthreads();   // compiler drains vmcnt before s_barrier (m97)

        short8 af[4], bfr[4];
#pragma unroll
        for (int i = 0; i < 4; i++) af[i]  = *(const short8*)&As[wm + i * 16 + l15][quad * 8];
#pragma unroll
        for (int i = 0; i < 4; i++) bfr[i] = *(const short8*)&Bs[wn + i * 16 + l15][quad * 8];
#pragma unroll
        for (int i = 0; i < 4; i++)
#pragma unroll
            for (int j = 0; j < 4; j++)
                acc[i][j] = __builtin_amdgcn_mfma_f32_16x16x32_bf16(af[i], bfr[j], acc[i][j], 0, 0, 0);
        __syncthreads();
    }

    const int f = (MODE == 2) ? *flagp : 0;

    // epilogue: D lane map col=lane&15, row=quad*4+r (verified m89/m91)
#pragma unroll
    for (int i = 0; i < 4; i++) {
#pragma unroll
        for (int j = 0; j < 4; j++) {
            const int col = bn + wn + j * 16 + l15;
            float bias; bool sig = false;
            if (MODE == 1) {
                if      (col < KK)     { bias = bf2f(b0[col]); }
                else if (col < 2 * KK) { bias = bf2f(b1[col - KK]);     sig = true; }
                else if (col < 3 * KK) { bias = bf2f(b2[col - 2 * KK]); sig = true; }
                else                   { bias = bf2f(b3[col - 3 * KK]); }
            } else {
                bias = bf2f(b0[col]);
            }
#pragma unroll
            for (int r = 0; r < 4; r++) {
                const int row = bm + wm + i * 16 + quad * 4 + r;
                float v = acc[i][j][r] + bias;
                if (sig) v = 1.f / (1.f + __expf(-v));
                const size_t idx = (size_t)row * ldc + coloff + col;
                if (MODE == 1)      ((float*)Cv)[idx]  = v;
                else if (MODE == 0) ((ushort*)Cv)[idx] = f2bf(v);
                else { if (f) ((float*)Cv)[idx] = v; else ((ushort*)Cv)[idx] = f2bf(v); }
            }
        }
    }
}

// ---------------- sequential gated scan, K-split for occupancy ----------------
// qkgv: (B*T, 2560) fp32 rows = [q(512) | k(512) | g(512) | v(1024)]
// grid (VD/16, B, 2): blockIdx.z = k-half -> 512 blocks = 2 blocks/CU = 2 waves/SIMD (TLP).
// Block: 256 thr, 16 v columns, K-half = 256. Wave-local map: kg = lane>>2 (16 groups of
// 16 k), vl = lane&3, v = v0 + wave*4 + vl. States: 16 fp32 regs/thread.
// Reduce: 4x shfl_xor in-wave (kg bits are lane bits 2..5), no LDS reduce, no 2nd barrier.
// Partial (k-half) outputs in fp32 pout[2][B][T][VD]; combine_k sums + converts.
// LDS layout per 256-float array: [m][kg] granule transpose -- float4 of (kg,m) at
// float offset m*64 + kg*4. Reads per m: 16 granules x 4-lane broadcast (min cycles);
// writes: 64 lanes -> 64 distinct granules (bijective, min cycles).
// Triple-buffered, distance-3 register pipeline (T14): step t ds-writes row t+1
// (loaded 2 steps ago, vmcnt long landed), issues loads for row t+3, computes row t.
__global__ __launch_bounds__(256, 2) void scan_k(const float* __restrict__ qkgv,
                                                 float* __restrict__ pout)
{
    const int b    = blockIdx.y;
    const int v0   = blockIdx.x * 16;
    const int kz   = blockIdx.z;          // k-half
    const int tid  = threadIdx.x;
    const int lane = tid & 63;
    const int wave = tid >> 6;
    const int kg   = lane >> 2;           // 0..15
    const int vl   = lane & 3;
    const int vloc = wave * 4 + vl;       // 0..15
    const int myv  = v0 + vloc;

    __shared__ float sq[3][256], sk[3][256], sg[3][256], sv[3][16];

    float s[16];
#pragma unroll
    for (int j = 0; j < 16; j++) s[j] = 0.f;

    const size_t rowbase = (size_t)b * TB * 2560;

    // staging roles: wave 0 -> q seg, 1 -> k seg, 2 -> g seg, 3 (lanes 0..3) -> v chunk.
    // Each active thread stages exactly one float4 per row.
    const int  srole = wave;
    const bool sact  = (srole < 3) || (lane < 4);
    const int  goff  = (srole < 3) ? srole * 512 + kz * 256 + lane * 4
                                   : 1536 + v0 + lane * 4;
    const int  slotf = (srole < 3) ? ((lane & 3) * 16 + (lane >> 2)) * 4   // [m][kg] transpose
                                   : lane * 4;

    float4 R0 = {0,0,0,0}, R1 = {0,0,0,0}, R2 = {0,0,0,0};

    { // prologue: rows 0,1,2 -> R0,R1,R2; stage row 0 -> buf 0
        const float* r0 = qkgv + rowbase;
        if (sact) {
            R0 = *(const float4*)&r0[goff];
            R1 = *(const float4*)&r0[2560 + goff];
            R2 = *(const float4*)&r0[5120 + goff];
        }
        if (srole == 0)      *(float4*)&sq[0][slotf] = R0;
        else if (srole == 1) *(float4*)&sk[0][slotf] = R0;
        else if (srole == 2) *(float4*)&sg[0][slotf] = R0;
        else if (lane < 4)   *(float4*)&sv[0][slotf] = R0;
        __syncthreads();
    }

    // step t: ds_write reg (t+1)%3 (row t+1) -> buf (t+1)%3; load row t+3 -> reg t%3;
    //         compute row t from buf t%3; in-wave reduce; one barrier.
#define SCAN_STEP(T, RW, RL, BW_, BC_)                                              \
    {                                                                               \
        const int t_ = (T);                                                         \
        if (t_ + 1 < TB) {                                                          \
            if (srole == 0)      *(float4*)&sq[BW_][slotf] = RW;                    \
            else if (srole == 1) *(float4*)&sk[BW_][slotf] = RW;                    \
            else if (srole == 2) *(float4*)&sg[BW_][slotf] = RW;                    \
            else if (lane < 4)   *(float4*)&sv[BW_][slotf] = RW;                    \
        }                                                                           \
        if (t_ + 3 < TB && sact) {                                                  \
            const float* row_ = qkgv + rowbase + (size_t)(t_ + 3) * 2560;           \
            RL = *(const float4*)&row_[goff];                                       \
        }                                                                           \
        if (t_ < TB) {                                                              \
            const float vv = sv[BC_][vloc];                                         \
            float po0, po1, po2, po3;                                               \
            _Pragma("unroll")                                                       \
            for (int m = 0; m < 4; m++) {                                           \
                const int off = m * 64 + kg * 4;                                    \
                float4 g4 = *(const float4*)&sg[BC_][off];                          \
                float4 k4 = *(const float4*)&sk[BC_][off];                          \
                float4 q4 = *(const float4*)&sq[BC_][off];                          \
                float* sm = &s[m * 4];                                              \
                sm[0] = fmaf(sm[0], g4.x, k4.x * vv);                               \
                sm[1] = fmaf(sm[1], g4.y, k4.y * vv);                               \
                sm[2] = fmaf(sm[2], g4.z, k4.z * vv);                               \
                sm[3] = fmaf(sm[3], g4.w, k4.w * vv);                               \
                float pm;                                                           \
                pm = q4.x * sm[0];                                                  \
                pm = fmaf(q4.y, sm[1], pm);                                         \
                pm = fmaf(q4.z, sm[2], pm);                                         \
                pm = fmaf(q4.w, sm[3], pm);                                         \
                if (m == 0) po0 = pm; else if (m == 1) po1 = pm;                    \
                else if (m == 2) po2 = pm; else po3 = pm;                           \
            }                                                                       \
            float po = (po0 + po1) + (po2 + po3);                                   \
            po += __shfl_xor(po, 4, 64);                                            \
            po += __shfl_xor(po, 8, 64);                                            \
            po += __shfl_xor(po, 16, 64);                                           \
            po += __shfl_xor(po, 32, 64);                                           \
            if (kg == 0)                                                            \
                pout[(((size_t)kz * BB + b) * TB + t_) * VD + myv] = po;            \
        }                                                                           \
        __syncthreads();                                                            \
    }

    for (int t = 0; t < TB; t += 3) {
        SCAN_STEP(t,     R1, R0, 1, 0);
        SCAN_STEP(t + 1, R2, R1, 2, 1);
        SCAN_STEP(t + 2, R0, R2, 0, 2);
    }
#undef SCAN_STEP
}

// ---------------- combine the two k-half partials -> bf16 ----------------
__global__ __launch_bounds__(256) void combine_k(const float* __restrict__ pout,
                                                 ushort* __restrict__ outp) {
    const size_t i = ((size_t)blockIdx.x * 256 + threadIdx.x) * 4;
    float4 a = *(const float4*)&pout[i];
    float4 c = *(const float4*)&pout[(size_t)NTOK * VD + i];
    ushort4 o;
    o.x = f2bf(a.x + c.x); o.y = f2bf(a.y + c.y);
    o.z = f2bf(a.z + c.z); o.w = f2bf(a.w + c.w);
    *(ushort4*)&outp[i] = o;
}

extern "C" void kernel_launch(void* const* d_in, const int* in_sizes, int n_in,
                              void* d_out, int out_size, void* d_ws, size_t ws_size,
                              hipStream_t stream) {
    const int*  ids = (const int*)d_in[0];
    const void* emb = d_in[1];
    const void* Wq  = d_in[2];
    const void* bq  = d_in[3];
    const void* Wk  = d_in[4];
    const void* bk  = d_in[5];
    const void* Wg  = d_in[6];
    const void* bg  = d_in[7];
    const void* Wv  = d_in[8];
    const void* bv  = d_in[9];
    const void* Wo  = d_in[10];
    const void* bo  = d_in[11];
    const void* Wh  = d_in[12];
    const void* bh  = d_in[13];
    (void)in_sizes; (void)n_in; (void)out_size; (void)ws_size;

    // ---- ws layout (~56 MB total) ----
    char* p = (char*)d_ws;
    auto alloc = [&](size_t bytes) { char* r = p; p += (bytes + 255) & ~(size_t)255; return (void*)r; };
    int*    flagp = (int*)alloc(4);
    ushort* biasc = (ushort*)alloc((size_t)39168 * 2);
    ushort* bqc = biasc, *bkc = biasc + 1024, *bgc = biasc + 2048;
    ushort* bvc = biasc + 3072, *boc = biasc + 5120, *bhc = biasc + 7168;
    ushort* Wcat  = (ushort*)alloc((size_t)NL * 2560 * HH * 2);
    ushort* Wot   = (ushort*)alloc((size_t)NL * OO * VD * 2);
    ushort* h     = (ushort*)alloc((size_t)NTOK * HH * 2);
    ushort* Whalf = (ushort*)alloc((size_t)NHALF * OO * 2);

    // ---- transient buffers live inside d_out (dead before head GEMM writes it) ----
    float*  qkgv  = (float*)d_out;                                        // 42 MB
    ushort* scano = (ushort*)((char*)d_out + (size_t)NTOK * 2560 * 4);    // +8.4 MB
    float*  pout  = (float*)((char*)d_out + (size_t)NTOK * 2560 * 4
                                          + (size_t)NTOK * VD * 2);       // +33.6 MB (<262 MB)

    // ---- dtype probe + bias normalize ----
    probe_k<<<1, 256, 0, stream>>>((const ushort*)emb, flagp);
    cvt_bias_k<<<(NL*KK + 255) / 256, 256, 0, stream>>>(bq, bqc, NL*KK, flagp);
    cvt_bias_k<<<(NL*KK + 255) / 256, 256, 0, stream>>>(bk, bkc, NL*KK, flagp);
    cvt_bias_k<<<(NL*KK + 255) / 256, 256, 0, stream>>>(bg, bgc, NL*KK, flagp);
    cvt_bias_k<<<(NL*VD + 255) / 256, 256, 0, stream>>>(bv, bvc, NL*VD, flagp);
    cvt_bias_k<<<(NL*OO + 255) / 256, 256, 0, stream>>>(bo, boc, NL*OO, flagp);
    cvt_bias_k<<<(NVOC  + 255) / 256, 256, 0, stream>>>(bh, bhc, NVOC,  flagp);

    // ---- weight transposes (normalize to bf16) ----
    for (int l = 0; l < NL; l++) {
        ushort* Wc = Wcat + (size_t)l * 2560 * HH;
        transpose_k<<<dim3(KK/32, HH/32), 256, 0, stream>>>(Wq, (size_t)l*HH*KK, Wc,                   HH, KK, flagp);
        transpose_k<<<dim3(KK/32, HH/32), 256, 0, stream>>>(Wk, (size_t)l*HH*KK, Wc + (size_t)KK*HH,   HH, KK, flagp);
        transpose_k<<<dim3(KK/32, HH/32), 256, 0, stream>>>(Wg, (size_t)l*HH*KK, Wc + (size_t)2*KK*HH, HH, KK, flagp);
        transpose_k<<<dim3(VD/32, HH/32), 256, 0, stream>>>(Wv, (size_t)l*HH*VD, Wc + (size_t)3*KK*HH, HH, VD, flagp);
        transpose_k<<<dim3(OO/32, VD/32), 256, 0, stream>>>(Wo, (size_t)l*VD*OO, Wot + (size_t)l*OO*VD, VD, OO, flagp);
    }

    // ---- embedding ----
    gather_k<<<NTOK, 256, 0, stream>>>(ids, emb, h, flagp);

    // ---- layers ----
    for (int l = 0; l < NL; l++) {
        const ushort* Wc = Wcat + (size_t)l * 2560 * HH;
        gemm_bt<1><<<dim3(2560/128, NTOK/128), 256, 0, stream>>>(
            h, Wc, qkgv, bqc + l*KK, bkc + l*KK, bgc + l*KK, bvc + l*VD,
            HH, 2560, 0, flagp);
        scan_k<<<dim3(VD/16, BB, 2), 256, 0, stream>>>(qkgv, pout);
        combine_k<<<(NTOK * VD / 4) / 256, 256, 0, stream>>>(pout, scano);
        gemm_bt<0><<<dim3(OO/128, NTOK/128), 256, 0, stream>>>(
            scano, Wot + (size_t)l*OO*VD, h, boc + l*OO, nullptr, nullptr, nullptr,
            VD, OO, 0, flagp);
    }

    // ---- LM head: transpose W_head chunk -> GEMM, twice (ws budget) ----
    for (int c0 = 0; c0 < NVOC; c0 += NHALF) {
        transpose_k<<<dim3(NHALF/32, OO/32), 256, 0, stream>>>(Wh, (size_t)c0, Whalf, OO, NVOC, flagp);
        gemm_bt<2><<<dim3(NHALF/128, NTOK/128), 256, 0, stream>>>(
            h, Whalf, d_out, bhc + c0, nullptr, nullptr, nullptr,
            OO, NVOC, c0, flagp);
    }
}